// Round 10
// baseline (334.027 us; speedup 1.0000x reference)
//
#include <hip/hip_runtime.h>
#include <hip/hip_bf16.h>

// GCN_simple: B=512 graphs x 128 nodes, FEAT=HID=512, OUT=10.
// Inputs fp32, output fp32. bf16 MFMA internally.
// R10: H1 full-size in LDS (128KB, correct size this time); phase-1 A staged
// per-kt via reg->cvt->ds_write double buffer (16KB, 1 barrier/kt, R8-proven);
// B fragments DIRECT from global (L2-resident weights) with 1-kt prefetch in
// BOTH phases; phase-2 K-loop is barrier-free.
// LDS map (bf16 elems, 144KB): H1 [0,65536), A-dbuf [65536,73728).
// redf/Sbuf scratch reuses the A-dbuf region once phase-1 is done.

typedef __attribute__((ext_vector_type(8))) short short8;
typedef __attribute__((ext_vector_type(4))) float f32x4;
typedef __attribute__((ext_vector_type(2))) unsigned int uint2v;

// RNE fp32->bf16 (finite), packed: b -> high 16, a -> low 16.
__device__ __forceinline__ unsigned int pack2_bf16(float a, float b) {
  unsigned int ua = __float_as_uint(a);
  unsigned int ub = __float_as_uint(b);
  ua += 0x7FFFu + ((ua >> 16) & 1u);
  ub += 0x7FFFu + ((ub >> 16) & 1u);
  return (ua >> 16) | (ub & 0xFFFF0000u);
}

__device__ __forceinline__ unsigned short bf16_rne(float a) {
  unsigned int ua = __float_as_uint(a);
  ua += 0x7FFFu + ((ua >> 16) & 1u);
  return (unsigned short)(ua >> 16);
}

__global__ __launch_bounds__(1024) void fused_gcn(
    const float* __restrict__ x,
    const __hip_bfloat16* __restrict__ W1t,   // [n][k] bf16
    const __hip_bfloat16* __restrict__ W2t,   // [n][k] bf16
    const float* __restrict__ b1,
    const float* __restrict__ b2,
    float* __restrict__ P)
{
  __shared__ __align__(16) __hip_bfloat16 smem[73728];   // 144 KB

  const int t  = threadIdx.x;
  const int g  = blockIdx.x;          // graph id
  const int wave = t >> 6;
  const int l    = t & 63;
  const int q    = l >> 4;
  const int r16  = l & 15;
  const int wm   = (wave & 1) * 64;
  const int wn   = (wave >> 1) * 64;

  __hip_bfloat16* H1 = smem;                 // [0,65536)
  __hip_bfloat16* Ab = smem + 65536;         // 2 bufs x 4096 elems (8KB each)

  // phase-1 A staging: thread (arow=t>>3, kq=t&7) loads f32x4, packs, ds_writes
  const int arow = t >> 3;
  const int kq   = t & 7;
  const float* ga = x + ((size_t)g * 128 + arow) * 512 + kq * 4;
  const int awoff = arow * 32 + (((kq >> 1) ^ ((arow >> 1) & 3)) << 3) + (kq & 1) * 4;

  // B-fragment global base (row-major [n][k]; quads of a row share a 64B line)
  const size_t bfo = (size_t)(wn + r16) * 512 + q * 8;

  f32x4 acc[4][4];
#pragma unroll
  for (int i = 0; i < 4; ++i)
#pragma unroll
    for (int j = 0; j < 4; ++j)
      acc[i][j] = (f32x4)0.0f;

  // ---------------- phase 1: C1 = x_g @ W1 (1 barrier/kt) ----------------
  {
    short8 bcur[4];
#pragma unroll
    for (int j = 0; j < 4; ++j)
      bcur[j] = *(const short8*)(const void*)(W1t + bfo + (size_t)j * 16 * 512);
    {
      const f32x4 a0 = *(const f32x4*)(const void*)ga;
      uint2v w;
      w[0] = pack2_bf16(a0[0], a0[1]);
      w[1] = pack2_bf16(a0[2], a0[3]);
      *(uint2v*)(void*)(Ab + awoff) = w;
    }
    for (int kt = 0; kt < 16; ++kt) {
      const int cur = kt & 1;
      const int nxt = cur ^ 1;
      __syncthreads();   // writes of buf[cur] visible; buf[nxt] free

      f32x4 aN;
      short8 bnxt[4];
      if (kt < 15) {
        const int ko = (kt + 1) * 32;
        aN = *(const f32x4*)(const void*)(ga + ko);
#pragma unroll
        for (int j = 0; j < 4; ++j)
          bnxt[j] = *(const short8*)(const void*)(W1t + bfo + (size_t)j * 16 * 512 + ko);
      }

      short8 af[4];
#pragma unroll
      for (int i = 0; i < 4; ++i) {
        const int row = wm + i * 16 + r16;
        const int c   = (q ^ ((row >> 1) & 3)) << 3;
        af[i] = *(const short8*)(const void*)(Ab + cur * 4096 + row * 32 + c);
      }
#pragma unroll
      for (int i = 0; i < 4; ++i)
#pragma unroll
        for (int j = 0; j < 4; ++j)
          acc[i][j] = __builtin_amdgcn_mfma_f32_16x16x32_bf16(af[i], bcur[j], acc[i][j], 0, 0, 0);

      if (kt < 15) {
        uint2v w;
        w[0] = pack2_bf16(aN[0], aN[1]);
        w[1] = pack2_bf16(aN[2], aN[3]);
        *(uint2v*)(void*)(Ab + nxt * 4096 + awoff) = w;
#pragma unroll
        for (int j = 0; j < 4; ++j) bcur[j] = bnxt[j];
      }
    }
  }
  __syncthreads();   // A-dbuf dead -> redf/Sbuf scratch usable

  float* redf = (float*)(Ab);              // 1024 f32 (4 KB)
  float* Sbuf = (float*)(Ab + 2048);       // 512 f32  (2 KB)

  // ---- epilogue-1: H1 = relu(...) bf16 into LDS ----
  // C/D layout: col = lane&15, row = quad*4 + reg
  if (g == 0) {
    float sj[4];
#pragma unroll
    for (int j = 0; j < 4; ++j) {
      float a = 0.0f;
#pragma unroll
      for (int i = 0; i < 4; ++i)
#pragma unroll
        for (int r = 0; r < 4; ++r)
          a += acc[i][j][r];
      a += __shfl_xor(a, 16, 64);
      a += __shfl_xor(a, 32, 64);
      sj[j] = a;
    }
    if (q == 0) {
#pragma unroll
      for (int j = 0; j < 4; ++j) redf[wave * 64 + j * 16 + r16] = sj[j];
    }
    __syncthreads();
    if (t < 512)
      Sbuf[t] = redf[((t >> 6) * 2) * 64 + (t & 63)] +
                redf[((t >> 6) * 2 + 1) * 64 + (t & 63)];
    __syncthreads();
#pragma unroll
    for (int j = 0; j < 4; ++j) {
      const int col = wn + j * 16 + r16;
      const float bv = b1[col];
      const float Sv = Sbuf[col];
#pragma unroll
      for (int i = 0; i < 4; ++i)
#pragma unroll
        for (int r = 0; r < 4; ++r) {
          const int row = wm + i * 16 + q * 4 + r;
          const float v = fmaxf((Sv + acc[i][j][r]) * (1.0f / 129.0f) + bv, 0.0f);
          const float o = __shfl_xor(v, 1, 64);
          if ((r16 & 1) == 0) {
            const int sl = (col >> 3) ^ (row & 7);
            *(unsigned int*)(void*)(H1 + row * 512 + sl * 8 + (col & 7)) = pack2_bf16(v, o);
          }
        }
    }
  } else {
#pragma unroll
    for (int j = 0; j < 4; ++j) {
      const int col = wn + j * 16 + r16;
      const float bv = b1[col];
#pragma unroll
      for (int i = 0; i < 4; ++i)
#pragma unroll
        for (int r = 0; r < 4; ++r) {
          const int row = wm + i * 16 + q * 4 + r;
          const float v = fmaxf(acc[i][j][r] + bv, 0.0f);
          const float o = __shfl_xor(v, 1, 64);
          if ((r16 & 1) == 0) {
            const int sl = (col >> 3) ^ (row & 7);
            *(unsigned int*)(void*)(H1 + row * 512 + sl * 8 + (col & 7)) = pack2_bf16(v, o);
          }
        }
    }
  }
  __syncthreads();   // H1 complete

  // ---------------- phase 2: C2 = H1 @ W2 (no barriers) ----------------
#pragma unroll
  for (int i = 0; i < 4; ++i)
#pragma unroll
    for (int j = 0; j < 4; ++j)
      acc[i][j] = (f32x4)0.0f;
  {
    short8 bcur[4];
#pragma unroll
    for (int j = 0; j < 4; ++j)
      bcur[j] = *(const short8*)(const void*)(W2t + bfo + (size_t)j * 16 * 512);
    for (int kt = 0; kt < 16; ++kt) {
      short8 af[4];
#pragma unroll
      for (int i = 0; i < 4; ++i) {
        const int row = wm + i * 16 + r16;
        const int sl  = (kt * 4 + q) ^ (row & 7);
        af[i] = *(const short8*)(const void*)(H1 + row * 512 + sl * 8);
      }
      short8 bnxt[4];
      if (kt < 15) {
        const int ko = (kt + 1) * 32;
#pragma unroll
        for (int j = 0; j < 4; ++j)
          bnxt[j] = *(const short8*)(const void*)(W2t + bfo + (size_t)j * 16 * 512 + ko);
      }
#pragma unroll
      for (int i = 0; i < 4; ++i)
#pragma unroll
        for (int j = 0; j < 4; ++j)
          acc[i][j] = __builtin_amdgcn_mfma_f32_16x16x32_bf16(af[i], bcur[j], acc[i][j], 0, 0, 0);
#pragma unroll
      for (int j = 0; j < 4; ++j) bcur[j] = bnxt[j];
    }
  }
  __syncthreads();   // H1 reads done; scratch reuse safe

  // ---- epilogue-2: fused mean-pool of relu(C2 + b2) ----
  float pj[4];
  if (g == 0) {
    float sj[4];
#pragma unroll
    for (int j = 0; j < 4; ++j) {
      float a = 0.0f;
#pragma unroll
      for (int i = 0; i < 4; ++i)
#pragma unroll
        for (int r = 0; r < 4; ++r)
          a += acc[i][j][r];
      a += __shfl_xor(a, 16, 64);
      a += __shfl_xor(a, 32, 64);
      sj[j] = a;
    }
    if (q == 0) {
#pragma unroll
      for (int j = 0; j < 4; ++j) redf[wave * 64 + j * 16 + r16] = sj[j];
    }
    __syncthreads();
    if (t < 512)
      Sbuf[t] = redf[((t >> 6) * 2) * 64 + (t & 63)] +
                redf[((t >> 6) * 2 + 1) * 64 + (t & 63)];
    __syncthreads();
#pragma unroll
    for (int j = 0; j < 4; ++j) {
      const float bv = b2[wn + j * 16 + r16];
      const float Sv = Sbuf[wn + j * 16 + r16];
      float a = 0.0f;
#pragma unroll
      for (int i = 0; i < 4; ++i)
#pragma unroll
        for (int r = 0; r < 4; ++r)
          a += fmaxf((Sv + acc[i][j][r]) * (1.0f / 129.0f) + bv, 0.0f);
      a += __shfl_xor(a, 16, 64);
      a += __shfl_xor(a, 32, 64);
      pj[j] = a;
    }
  } else {
#pragma unroll
    for (int j = 0; j < 4; ++j) {
      const float bv = b2[wn + j * 16 + r16];
      float a = 0.0f;
#pragma unroll
      for (int i = 0; i < 4; ++i)
#pragma unroll
        for (int r = 0; r < 4; ++r)
          a += fmaxf(acc[i][j][r] + bv, 0.0f);
      a += __shfl_xor(a, 16, 64);
      a += __shfl_xor(a, 32, 64);
      pj[j] = a;
    }
  }
  __syncthreads();
  if (q == 0) {
#pragma unroll
    for (int j = 0; j < 4; ++j) redf[wave * 64 + j * 16 + r16] = pj[j];
  }
  __syncthreads();
  if (t < 512)
    P[(size_t)g * 512 + t] =
        (redf[((t >> 6) * 2) * 64 + (t & 63)] +
         redf[((t >> 6) * 2 + 1) * 64 + (t & 63)]) * (1.0f / 128.0f);
}

// Wf[c][:] = W3[c][:]@Wlin (wave per row); bfv for c<10.
__global__ void fold_w(const float* __restrict__ W3,
                       const float* __restrict__ Wlin,
                       const float* __restrict__ b3,
                       const float* __restrict__ blin,
                       float* __restrict__ Wf, float* __restrict__ bfv) {
  const int c = blockIdx.x;
  const int l = threadIdx.x;
  float acc[10];
#pragma unroll
  for (int o = 0; o < 10; ++o) acc[o] = 0.0f;
  for (int n = l; n < 512; n += 64) {
    const float wv = W3[c * 512 + n];
#pragma unroll
    for (int o = 0; o < 10; ++o) acc[o] += wv * Wlin[n * 10 + o];
  }
#pragma unroll
  for (int off = 32; off; off >>= 1)
#pragma unroll
    for (int o = 0; o < 10; ++o) acc[o] += __shfl_down(acc[o], off, 64);
  if (l == 0) {
#pragma unroll
    for (int o = 0; o < 10; ++o) Wf[c * 10 + o] = acc[o];
  }
  if (c < 10) {
    float s = 0.0f;
    for (int k = l; k < 512; k += 64) s += b3[k] * Wlin[k * 10 + c];
#pragma unroll
    for (int off = 32; off; off >>= 1) s += __shfl_down(s, off, 64);
    if (l == 0) bfv[c] = s + blin[c];
  }
}

// out[m][:] = P[m][:] @ Wf + bfv
__global__ void final_out(const float* __restrict__ P,
                          const float* __restrict__ Wf,
                          const float* __restrict__ bfv,
                          float* __restrict__ out) {
  const int m = blockIdx.x;
  const int l = threadIdx.x;
  float acc[10];
#pragma unroll
  for (int o = 0; o < 10; ++o) acc[o] = 0.0f;
  for (int c = l; c < 512; c += 64) {
    const float p = P[m * 512 + c];
#pragma unroll
    for (int o = 0; o < 10; ++o) acc[o] += p * Wf[c * 10 + o];
  }
#pragma unroll
  for (int off = 32; off; off >>= 1)
#pragma unroll
    for (int o = 0; o < 10; ++o) acc[o] += __shfl_down(acc[o], off, 64);
  if (l == 0) {
#pragma unroll
    for (int o = 0; o < 10; ++o) out[m * 10 + o] = acc[o] + bfv[o];
  }
}

// Wt[n][k] = bf16(W[k][n]) for W1 (z=0) and W2 (z=1)
__global__ void transpose512x2(const float* __restrict__ Wa,
                               const float* __restrict__ Wb,
                               unsigned short* __restrict__ Wat,
                               unsigned short* __restrict__ Wbt) {
  const float* W = blockIdx.z ? Wb : Wa;
  unsigned short* Wt = blockIdx.z ? Wbt : Wat;
  __shared__ float tile[32][33];
  const int tx = threadIdx.x, ty = threadIdx.y;
  tile[ty][tx] = W[(blockIdx.y * 32 + ty) * 512 + blockIdx.x * 32 + tx];
  __syncthreads();
  Wt[(blockIdx.x * 32 + ty) * 512 + blockIdx.y * 32 + tx] = bf16_rne(tile[tx][ty]);
}

extern "C" void kernel_launch(void* const* d_in, const int* in_sizes, int n_in,
                              void* d_out, int out_size, void* d_ws, size_t ws_size,
                              hipStream_t stream) {
  const float* x    = (const float*)d_in[0];
  const float* W1   = (const float*)d_in[1];
  const float* b1   = (const float*)d_in[2];
  const float* W2   = (const float*)d_in[3];
  const float* b2   = (const float*)d_in[4];
  const float* W3   = (const float*)d_in[5];
  const float* b3   = (const float*)d_in[6];
  const float* Wlin = (const float*)d_in[7];
  const float* blin = (const float*)d_in[8];
  float* out = (float*)d_out;

  char* ws = (char*)d_ws;
  unsigned short* W1t = (unsigned short*)ws;                 // 512 KB
  unsigned short* W2t = W1t + 512 * 512;                     // 512 KB
  float* P            = (float*)(W2t + 512 * 512);           // 1 MB
  float* Wf           = P + 512 * 512;                       // 20 KB
  float* bfv          = Wf + 512 * 10;                       // 40 B

  transpose512x2<<<dim3(16, 16, 2), dim3(32, 32), 0, stream>>>(W1, W2, W1t, W2t);
  fold_w<<<512, 64, 0, stream>>>(W3, Wlin, b3, blin, Wf, bfv);

  fused_gcn<<<512, 1024, 0, stream>>>(
      x, (const __hip_bfloat16*)W1t, (const __hip_bfloat16*)W2t, b1, b2, P);

  final_out<<<512, 64, 0, stream>>>(P, Wf, bfv, out);
}

// Round 11
// 292.512 us; speedup vs baseline: 1.1419x; 1.1419x over previous
//
#include <hip/hip_runtime.h>
#include <hip/hip_bf16.h>

// GCN_simple: B=512 graphs x 128 nodes, FEAT=HID=512, OUT=10.
// Inputs fp32, output fp32. bf16 MFMA internally.
// R11 = R8 structure (proven fastest: DMA-shared B staging, H1-in-LDS fusion)
// + NONTEMPORAL x loads so the 74MB x stream doesn't evict the 1MB of
// weights from per-XCD L2 (R10 showed per-wave global B reads stall: all
// pipes <20% busy -> L3-latency-bound).
// LDS map (bf16 elems, 160KB):
//   [0,65536)      H1 (row r at r*512; chunk c at slot c^(r&7))
//   [0,8192)       phase-1 A dbuf (2x8KB)      — overlaps H1 rows 0..15
//   [49152,81920)  phase-1 B dbuf (2x32KB)     — overlaps H1 rows 96..127+tail
//   [65536,81920)  phase-2 B single buf (32KB) — outside H1
//   [65536,..)     f32 scratch redf[1024], Sbuf[512] (only when B dead)

typedef __attribute__((ext_vector_type(8))) short short8;
typedef __attribute__((ext_vector_type(4))) float f32x4;
typedef __attribute__((ext_vector_type(2))) unsigned int uint2v;

#define AS_G __attribute__((address_space(1)))
#define AS_L __attribute__((address_space(3)))

__device__ __forceinline__ void gload_lds16(const void* g, void* l) {
  __builtin_amdgcn_global_load_lds((const AS_G void*)g, (AS_L void*)l, 16, 0, 0);
}

// RNE fp32->bf16 (finite), packed: b -> high 16, a -> low 16.
__device__ __forceinline__ unsigned int pack2_bf16(float a, float b) {
  unsigned int ua = __float_as_uint(a);
  unsigned int ub = __float_as_uint(b);
  ua += 0x7FFFu + ((ua >> 16) & 1u);
  ub += 0x7FFFu + ((ub >> 16) & 1u);
  return (ua >> 16) | (ub & 0xFFFF0000u);
}

__device__ __forceinline__ unsigned short bf16_rne(float a) {
  unsigned int ua = __float_as_uint(a);
  ua += 0x7FFFu + ((ua >> 16) & 1u);
  return (unsigned short)(ua >> 16);
}

__global__ __launch_bounds__(1024) void fused_gcn(
    const float* __restrict__ x,
    const __hip_bfloat16* __restrict__ W1t,   // [n][k] bf16
    const __hip_bfloat16* __restrict__ W2t,   // [n][k] bf16
    const float* __restrict__ b1,
    const float* __restrict__ b2,
    float* __restrict__ P)
{
  __shared__ __align__(16) __hip_bfloat16 smem[81920];   // 160 KB

  const int t  = threadIdx.x;
  const int g  = blockIdx.x;          // graph id 0..511
  const int wave = t >> 6;
  const int l    = t & 63;
  const int q    = l >> 4;
  const int r16  = l & 15;
  const int wm   = (wave & 1) * 64;
  const int wn   = (wave >> 1) * 64;

  // phase-1 A staging: thread (arow=t>>3, kq=t&7) loads f32x4 NT, packs, ds_writes
  const int arow = t >> 3;
  const int kq   = t & 7;
  const float* ga = x + ((size_t)g * 128 + arow) * 512 + kq * 4;
  const int awoff = arow * 32 + (((kq >> 1) ^ ((arow >> 1) & 3)) << 3) + (kq & 1) * 4;

  // B staging (both phases): row=t>>2, slot t&3 gets global chunk (t&3)^sw(row)
  const int brow = t >> 2;
  const int bgc  = (t & 3) ^ ((brow >> 1) & 3);
  const size_t boff = (size_t)brow * 512 + bgc * 8;
  const __hip_bfloat16* g1b0 = W1t + boff;
  const __hip_bfloat16* g1b1 = g1b0 + (size_t)256 * 512;

  f32x4 acc[4][4];
#pragma unroll
  for (int i = 0; i < 4; ++i)
#pragma unroll
    for (int j = 0; j < 4; ++j)
      acc[i][j] = (f32x4)0.0f;

  // ---------------- phase 1: C1 = x_g @ W1 (1 barrier/kt) ----------------
  {
    const f32x4 a0 = __builtin_nontemporal_load((const f32x4*)(const void*)ga);
    gload_lds16(g1b0, smem + 49152 + wave * 512);
    gload_lds16(g1b1, smem + 49152 + 8192 + wave * 512);
    uint2v w;
    w[0] = pack2_bf16(a0[0], a0[1]);
    w[1] = pack2_bf16(a0[2], a0[3]);
    *(uint2v*)(void*)(smem + awoff) = w;
  }
  for (int kt = 0; kt < 16; ++kt) {
    const int cur = kt & 1;
    const int nxt = cur ^ 1;
    __syncthreads();   // staging(kt) visible; bufs(nxt) free

    f32x4 aN;
    if (kt < 15) {
      const int ko = (kt + 1) * 32;
      aN = __builtin_nontemporal_load((const f32x4*)(const void*)(ga + ko));
      gload_lds16(g1b0 + ko, smem + 49152 + nxt * 16384 + wave * 512);
      gload_lds16(g1b1 + ko, smem + 49152 + nxt * 16384 + 8192 + wave * 512);
    }

    short8 af[4], bfr[4];
#pragma unroll
    for (int i = 0; i < 4; ++i) {
      const int row = wm + i * 16 + r16;
      const int c   = (q ^ ((row >> 1) & 3)) << 3;
      af[i] = *(const short8*)(const void*)(smem + cur * 4096 + row * 32 + c);
    }
#pragma unroll
    for (int j = 0; j < 4; ++j) {
      const int row = wn + j * 16 + r16;
      const int c   = (q ^ ((row >> 1) & 3)) << 3;
      bfr[j] = *(const short8*)(const void*)(smem + 49152 + cur * 16384 + row * 32 + c);
    }
#pragma unroll
    for (int i = 0; i < 4; ++i)
#pragma unroll
      for (int j = 0; j < 4; ++j)
        acc[i][j] = __builtin_amdgcn_mfma_f32_16x16x32_bf16(af[i], bfr[j], acc[i][j], 0, 0, 0);

    if (kt < 15) {
      uint2v w;
      w[0] = pack2_bf16(aN[0], aN[1]);
      w[1] = pack2_bf16(aN[2], aN[3]);
      *(uint2v*)(void*)(smem + nxt * 4096 + awoff) = w;
    }
  }
  __syncthreads();   // staging dead; epilogue-1 may write H1 anywhere

  float* redf = (float*)(smem + 65536);   // 1024 f32 (4 KB)
  float* Sbuf = (float*)(smem + 67584);   // 512 f32  (2 KB)

  // ---- epilogue-1: H1 = relu(...) bf16 into LDS ----
  // C/D layout: col = lane&15, row = quad*4 + reg
  if (g == 0) {
    float sj[4];
#pragma unroll
    for (int j = 0; j < 4; ++j) {
      float a = 0.0f;
#pragma unroll
      for (int i = 0; i < 4; ++i)
#pragma unroll
        for (int r = 0; r < 4; ++r)
          a += acc[i][j][r];
      a += __shfl_xor(a, 16, 64);
      a += __shfl_xor(a, 32, 64);
      sj[j] = a;
    }
    if (q == 0) {
#pragma unroll
      for (int j = 0; j < 4; ++j) redf[wave * 64 + j * 16 + r16] = sj[j];
    }
    __syncthreads();
    if (t < 512)
      Sbuf[t] = redf[((t >> 6) * 2) * 64 + (t & 63)] +
                redf[((t >> 6) * 2 + 1) * 64 + (t & 63)];
    __syncthreads();
#pragma unroll
    for (int j = 0; j < 4; ++j) {
      const int col = wn + j * 16 + r16;
      const float bv = b1[col];
      const float Sv = Sbuf[col];
#pragma unroll
      for (int i = 0; i < 4; ++i)
#pragma unroll
        for (int r = 0; r < 4; ++r) {
          const int row = wm + i * 16 + q * 4 + r;
          const float v = fmaxf((Sv + acc[i][j][r]) * (1.0f / 129.0f) + bv, 0.0f);
          const float o = __shfl_xor(v, 1, 64);
          if ((r16 & 1) == 0) {
            const int sl = (col >> 3) ^ (row & 7);
            *(unsigned int*)(void*)(smem + row * 512 + sl * 8 + (col & 7)) = pack2_bf16(v, o);
          }
        }
    }
  } else {
#pragma unroll
    for (int j = 0; j < 4; ++j) {
      const int col = wn + j * 16 + r16;
      const float bv = b1[col];
#pragma unroll
      for (int i = 0; i < 4; ++i)
#pragma unroll
        for (int r = 0; r < 4; ++r) {
          const int row = wm + i * 16 + q * 4 + r;
          const float v = fmaxf(acc[i][j][r] + bv, 0.0f);
          const float o = __shfl_xor(v, 1, 64);
          if ((r16 & 1) == 0) {
            const int sl = (col >> 3) ^ (row & 7);
            *(unsigned int*)(void*)(smem + row * 512 + sl * 8 + (col & 7)) = pack2_bf16(v, o);
          }
        }
    }
  }

  // ---------------- phase 2: C2 = H1 @ W2 (B DMA single-buf) ----------------
#pragma unroll
  for (int i = 0; i < 4; ++i)
#pragma unroll
    for (int j = 0; j < 4; ++j)
      acc[i][j] = (f32x4)0.0f;

  const __hip_bfloat16* g2b0 = W2t + boff;
  const __hip_bfloat16* g2b1 = g2b0 + (size_t)256 * 512;

  for (int kt = 0; kt < 16; ++kt) {
    __syncthreads();   // protect Bbuf2 (and H1 writes at kt=0)
    const int ko = kt * 32;
    gload_lds16(g2b0 + ko, smem + 65536 + wave * 512);
    gload_lds16(g2b1 + ko, smem + 65536 + 8192 + wave * 512);
    __syncthreads();   // DMA complete

    short8 af[4], bfr[4];
#pragma unroll
    for (int i = 0; i < 4; ++i) {
      const int row = wm + i * 16 + r16;
      const int sl  = (kt * 4 + q) ^ (row & 7);
      af[i] = *(const short8*)(const void*)(smem + row * 512 + sl * 8);
    }
#pragma unroll
    for (int j = 0; j < 4; ++j) {
      const int row = wn + j * 16 + r16;
      const int c   = (q ^ ((row >> 1) & 3)) << 3;
      bfr[j] = *(const short8*)(const void*)(smem + 65536 + row * 32 + c);
    }
#pragma unroll
    for (int i = 0; i < 4; ++i)
#pragma unroll
      for (int j = 0; j < 4; ++j)
        acc[i][j] = __builtin_amdgcn_mfma_f32_16x16x32_bf16(af[i], bfr[j], acc[i][j], 0, 0, 0);
  }
  __syncthreads();   // Bbuf2 dead -> scratch

  // ---- epilogue-2: fused mean-pool of relu(C2 + b2) ----
  float pj[4];
  if (g == 0) {
    float sj[4];
#pragma unroll
    for (int j = 0; j < 4; ++j) {
      float a = 0.0f;
#pragma unroll
      for (int i = 0; i < 4; ++i)
#pragma unroll
        for (int r = 0; r < 4; ++r)
          a += acc[i][j][r];
      a += __shfl_xor(a, 16, 64);
      a += __shfl_xor(a, 32, 64);
      sj[j] = a;
    }
    if (q == 0) {
#pragma unroll
      for (int j = 0; j < 4; ++j) redf[wave * 64 + j * 16 + r16] = sj[j];
    }
    __syncthreads();
    if (t < 512)
      Sbuf[t] = redf[((t >> 6) * 2) * 64 + (t & 63)] +
                redf[((t >> 6) * 2 + 1) * 64 + (t & 63)];
    __syncthreads();
#pragma unroll
    for (int j = 0; j < 4; ++j) {
      const float bv = b2[wn + j * 16 + r16];
      const float Sv = Sbuf[wn + j * 16 + r16];
      float a = 0.0f;
#pragma unroll
      for (int i = 0; i < 4; ++i)
#pragma unroll
        for (int r = 0; r < 4; ++r)
          a += fmaxf((Sv + acc[i][j][r]) * (1.0f / 129.0f) + bv, 0.0f);
      a += __shfl_xor(a, 16, 64);
      a += __shfl_xor(a, 32, 64);
      pj[j] = a;
    }
  } else {
#pragma unroll
    for (int j = 0; j < 4; ++j) {
      const float bv = b2[wn + j * 16 + r16];
      float a = 0.0f;
#pragma unroll
      for (int i = 0; i < 4; ++i)
#pragma unroll
        for (int r = 0; r < 4; ++r)
          a += fmaxf(acc[i][j][r] + bv, 0.0f);
      a += __shfl_xor(a, 16, 64);
      a += __shfl_xor(a, 32, 64);
      pj[j] = a;
    }
  }
  __syncthreads();
  if (q == 0) {
#pragma unroll
    for (int j = 0; j < 4; ++j) redf[wave * 64 + j * 16 + r16] = pj[j];
  }
  __syncthreads();
  if (t < 512)
    P[(size_t)g * 512 + t] =
        (redf[((t >> 6) * 2) * 64 + (t & 63)] +
         redf[((t >> 6) * 2 + 1) * 64 + (t & 63)]) * (1.0f / 128.0f);
}

// Wf[c][:] = W3[c][:]@Wlin (wave per row); bfv for c<10.
__global__ void fold_w(const float* __restrict__ W3,
                       const float* __restrict__ Wlin,
                       const float* __restrict__ b3,
                       const float* __restrict__ blin,
                       float* __restrict__ Wf, float* __restrict__ bfv) {
  const int c = blockIdx.x;
  const int l = threadIdx.x;
  float acc[10];
#pragma unroll
  for (int o = 0; o < 10; ++o) acc[o] = 0.0f;
  for (int n = l; n < 512; n += 64) {
    const float wv = W3[c * 512 + n];
#pragma unroll
    for (int o = 0; o < 10; ++o) acc[o] += wv * Wlin[n * 10 + o];
  }
#pragma unroll
  for (int off = 32; off; off >>= 1)
#pragma unroll
    for (int o = 0; o < 10; ++o) acc[o] += __shfl_down(acc[o], off, 64);
  if (l == 0) {
#pragma unroll
    for (int o = 0; o < 10; ++o) Wf[c * 10 + o] = acc[o];
  }
  if (c < 10) {
    float s = 0.0f;
    for (int k = l; k < 512; k += 64) s += b3[k] * Wlin[k * 10 + c];
#pragma unroll
    for (int off = 32; off; off >>= 1) s += __shfl_down(s, off, 64);
    if (l == 0) bfv[c] = s + blin[c];
  }
}

// out[m][:] = P[m][:] @ Wf + bfv
__global__ void final_out(const float* __restrict__ P,
                          const float* __restrict__ Wf,
                          const float* __restrict__ bfv,
                          float* __restrict__ out) {
  const int m = blockIdx.x;
  const int l = threadIdx.x;
  float acc[10];
#pragma unroll
  for (int o = 0; o < 10; ++o) acc[o] = 0.0f;
  for (int c = l; c < 512; c += 64) {
    const float p = P[m * 512 + c];
#pragma unroll
    for (int o = 0; o < 10; ++o) acc[o] += p * Wf[c * 10 + o];
  }
#pragma unroll
  for (int off = 32; off; off >>= 1)
#pragma unroll
    for (int o = 0; o < 10; ++o) acc[o] += __shfl_down(acc[o], off, 64);
  if (l == 0) {
#pragma unroll
    for (int o = 0; o < 10; ++o) out[m * 10 + o] = acc[o] + bfv[o];
  }
}

// Wt[n][k] = bf16(W[k][n]) for W1 (z=0) and W2 (z=1)
__global__ void transpose512x2(const float* __restrict__ Wa,
                               const float* __restrict__ Wb,
                               unsigned short* __restrict__ Wat,
                               unsigned short* __restrict__ Wbt) {
  const float* W = blockIdx.z ? Wb : Wa;
  unsigned short* Wt = blockIdx.z ? Wbt : Wat;
  __shared__ float tile[32][33];
  const int tx = threadIdx.x, ty = threadIdx.y;
  tile[ty][tx] = W[(blockIdx.y * 32 + ty) * 512 + blockIdx.x * 32 + tx];
  __syncthreads();
  Wt[(blockIdx.x * 32 + ty) * 512 + blockIdx.y * 32 + tx] = bf16_rne(tile[tx][ty]);
}

extern "C" void kernel_launch(void* const* d_in, const int* in_sizes, int n_in,
                              void* d_out, int out_size, void* d_ws, size_t ws_size,
                              hipStream_t stream) {
  const float* x    = (const float*)d_in[0];
  const float* W1   = (const float*)d_in[1];
  const float* b1   = (const float*)d_in[2];
  const float* W2   = (const float*)d_in[3];
  const float* b2   = (const float*)d_in[4];
  const float* W3   = (const float*)d_in[5];
  const float* b3   = (const float*)d_in[6];
  const float* Wlin = (const float*)d_in[7];
  const float* blin = (const float*)d_in[8];
  float* out = (float*)d_out;

  char* ws = (char*)d_ws;
  unsigned short* W1t = (unsigned short*)ws;                 // 512 KB
  unsigned short* W2t = W1t + 512 * 512;                     // 512 KB
  float* P            = (float*)(W2t + 512 * 512);           // 1 MB
  float* Wf           = P + 512 * 512;                       // 20 KB
  float* bfv          = Wf + 512 * 10;                       // 40 B

  transpose512x2<<<dim3(16, 16, 2), dim3(32, 32), 0, stream>>>(W1, W2, W1t, W2t);
  fold_w<<<512, 64, 0, stream>>>(W3, Wlin, b3, blin, Wf, bfv);

  fused_gcn<<<512, 1024, 0, stream>>>(
      x, (const __hip_bfloat16*)W1t, (const __hip_bfloat16*)W2t, b1, b2, P);

  final_out<<<512, 64, 0, stream>>>(P, Wf, bfv, out);
}